// Round 1
// baseline (106.810 us; speedup 1.0000x reference)
//
#include <hip/hip_runtime.h>
#include <math.h>

#define EPS 1e-5f

constexpr int Bc = 64, Pc = 68, Hc = 64, Wc = 64;
constexpr int NPIX  = Hc * Wc;   // 4096 pixels per tile
constexpr int NTILE = Bc * Pc;   // 4352 tiles
constexpr int BLK   = 256;       // threads per block
constexpr int PPT   = NPIX / BLK; // 16 pixels per thread

// Block-wide sum reduction (256 threads = 4 waves of 64).
// sbuf must have >= 8 floats. Safe to call repeatedly.
__device__ __forceinline__ float block_reduce_sum(float v, float* sbuf) {
    __syncthreads();  // protect sbuf from previous use
    // 64-lane wave reduction
    #pragma unroll
    for (int o = 32; o > 0; o >>= 1) v += __shfl_down(v, o, 64);
    const int lane = threadIdx.x & 63;
    const int wid  = threadIdx.x >> 6;
    if (lane == 0) sbuf[wid] = v;
    __syncthreads();
    if (threadIdx.x == 0) {
        float s = sbuf[0] + sbuf[1] + sbuf[2] + sbuf[3];
        sbuf[4] = s;
    }
    __syncthreads();
    return sbuf[4];
}

__global__ __launch_bounds__(BLK)
void gauss_kld_tile_kernel(const float* __restrict__ hm,
                           const float* __restrict__ means,
                           const float* __restrict__ cov,
                           float* __restrict__ partial) {
    const int tile = blockIdx.x;
    const float* __restrict__ h = hm + (size_t)tile * NPIX;

    const float mx  = means[tile * 2 + 0];
    const float my  = means[tile * 2 + 1];
    const float s00 = cov[tile * 4 + 0];
    const float s01 = cov[tile * 4 + 1];
    const float s10 = cov[tile * 4 + 2];
    const float s11 = cov[tile * 4 + 3];
    const float det = s00 * s11 - s01 * s10 + EPS;
    const float inv_det = 1.0f / det;
    const float c_xx =  s11 * inv_det;
    const float c_xy = -(s01 + s10) * inv_det;
    const float c_yy =  s00 * inv_det;

    const int t = threadIdx.x;

    float lp[PPT];
    float hv[PPT];
    float esum = 0.0f;

    // Coalesced float4 loads: float4 index v = k*256 + t, pixels [4v, 4v+4)
    #pragma unroll
    for (int k = 0; k < PPT / 4; k++) {
        const int v = k * BLK + t;
        const float4 h4 = reinterpret_cast<const float4*>(h)[v];
        hv[k * 4 + 0] = h4.x;
        hv[k * 4 + 1] = h4.y;
        hv[k * 4 + 2] = h4.z;
        hv[k * 4 + 3] = h4.w;
        const int base = v * 4;
        #pragma unroll
        for (int c = 0; c < 4; c++) {
            const int idx = base + c;
            const float dy = (float)(idx >> 6) - my;   // row = y
            const float dx = (float)(idx & 63) - mx;   // col = x
            const float quad = c_xx * dx * dx + c_xy * dx * dy + c_yy * dy * dy;
            const float l = -0.5f * quad;
            lp[k * 4 + c] = l;
            esum += __expf(l);
        }
    }

    __shared__ float sbuf[8];
    const float S = block_reduce_sum(esum, sbuf);
    const float invS = 1.0f / S;

    float kl = 0.0f;
    #pragma unroll
    for (int i = 0; i < PPT; i++) {
        const float pr = __expf(lp[i]) * invS;
        const float hvi = hv[i];
        // xlogy(hm,hm) - hm*log(pr+EPS); hm>0 in this problem, guard anyway
        if (hvi > 0.0f) {
            kl += hvi * (__logf(hvi) - __logf(pr + EPS));
        } else {
            kl += -hvi * __logf(pr + EPS);
        }
    }

    const float tile_sum = block_reduce_sum(kl, sbuf);
    if (threadIdx.x == 0) partial[tile] = tile_sum;
}

__global__ __launch_bounds__(BLK)
void gauss_kld_reduce_kernel(const float* __restrict__ partial,
                             float* __restrict__ out) {
    float s = 0.0f;
    for (int i = threadIdx.x; i < NTILE; i += BLK) s += partial[i];
    __shared__ float sbuf[8];
    const float tot = block_reduce_sum(s, sbuf);
    if (threadIdx.x == 0) out[0] = tot / (float)NTILE;
}

extern "C" void kernel_launch(void* const* d_in, const int* in_sizes, int n_in,
                              void* d_out, int out_size, void* d_ws, size_t ws_size,
                              hipStream_t stream) {
    const float* hm    = (const float*)d_in[0];
    const float* means = (const float*)d_in[1];
    const float* cov   = (const float*)d_in[2];
    float* out = (float*)d_out;
    float* partial = (float*)d_ws;  // NTILE floats

    gauss_kld_tile_kernel<<<NTILE, BLK, 0, stream>>>(hm, means, cov, partial);
    gauss_kld_reduce_kernel<<<1, BLK, 0, stream>>>(partial, out);
}